// Round 4
// baseline (1233.603 us; speedup 1.0000x reference)
//
#include <hip/hip_runtime.h>

// Instant-NGP 2D hashgrid (L=16, T=2^20, F=2, N_MIN=16, b=2) + MLP 32->128->128->3.
// R4: R3's depth-1/2 pipeline, but gather state in plain local arrays with
// constant indices stamped inline via macro (NO struct, NO by-reference
// helper). R2/R3's Pref& escaped into an alloca SROA never promoted ->
// every gather bounced through scratch (WRITE_SIZE 613MB, VGPR_Count 84).
// Persistent grid: 768 blocks = exactly 3/CU (LDS-bound), ~21 tiles/wave so
// the prefetch pipeline warms once. No per-iteration barriers (hbuf is
// per-wave; w2T/biases read-only after the single init barrier).
//
// GEMM formulation: h^T = W^T x^T  (rows m = neurons, cols n = points).
//   mfma_f32_16x16x32_bf16 layouts (HW-verified per guide):
//     A[m][k]: m = lane&15, k = (lane>>4)*8 + j   (8 bf16 / lane)
//     B[k][n]: n = lane&15, k = (lane>>4)*8 + j
//     D[m][n]: n = lane&15, m = (lane>>4)*4 + r   (4 f32 / lane)
// Lane (quad, lo) encodes point lo at levels 4*quad .. 4*quad+3 == features
// k = quad*8 .. quad*8+7  ->  exactly its layer-1 B-fragment. No shuffle.

#define T_SIZE  (1u << 20)
#define HASH_Y  2654435761u

typedef __bf16 bf16x8 __attribute__((ext_vector_type(8)));
typedef float f32x4 __attribute__((ext_vector_type(4)));
typedef unsigned short u16x8 __attribute__((ext_vector_type(8)));
typedef unsigned short u16x4 __attribute__((ext_vector_type(4)));

static __device__ __forceinline__ unsigned short f2bf(float f) {
    union { float f; unsigned u; } v; v.f = f;
    unsigned u = v.u;
    u += 0x7fffu + ((u >> 16) & 1u);   // round-to-nearest-even
    return (unsigned short)(u >> 16);
}

static __device__ __forceinline__ f32x4 mfma16(u16x8 a, u16x8 b, f32x4 c) {
    return __builtin_amdgcn_mfma_f32_16x16x32_bf16(
        __builtin_bit_cast(bf16x8, a), __builtin_bit_cast(bf16x8, b), c, 0, 0, 0);
}

// Issue 16 table gathers for point PT, levels 4*quad..4*quad+3, into locals
// pf[16] / pwx[4] / pwy[4]. Macro (not function) so the destination stays a
// plain SROA-promotable local array at every expansion site.
#define ISSUE_GATHERS(PT)                                                        \
    {                                                                            \
        float2 _p = uv2[(PT)];                                                   \
        _Pragma("unroll")                                                        \
        for (int _i = 0; _i < 4; ++_i) {                                         \
            int _lvl = (quad << 2) + _i;                                         \
            unsigned _res = 16u << _lvl;                                         \
            float _px = _p.x * (float)_res, _py = _p.y * (float)_res;            \
            float _fx = floorf(_px), _fy = floorf(_py);                          \
            pwx[_i] = _px - _fx;                                                 \
            pwy[_i] = _py - _fy;                                                 \
            unsigned _cx = (unsigned)_fx, _cy = (unsigned)_fy;                   \
            unsigned _rp1 = _res + 1u;                                           \
            unsigned _hy0 = _cy * HASH_Y, _hy1 = (_cy + 1u) * HASH_Y;            \
            const unsigned _mask = T_SIZE - 1u;                                  \
            bool _dense = _lvl < 6;                                              \
            unsigned _i00 = _dense ? (_cx + _cy * _rp1)             : ((_cx ^ _hy0) & _mask);          \
            unsigned _i01 = _dense ? (_cx + (_cy + 1u) * _rp1)      : ((_cx ^ _hy1) & _mask);          \
            unsigned _i10 = _dense ? (_cx + 1u + _cy * _rp1)        : (((_cx + 1u) ^ _hy0) & _mask);   \
            unsigned _i11 = _dense ? (_cx + 1u + (_cy + 1u) * _rp1) : (((_cx + 1u) ^ _hy1) & _mask);   \
            const float2* _t2 = t2base + (size_t)_lvl * T_SIZE;                  \
            pf[4 * _i + 0] = _t2[_i00];                                          \
            pf[4 * _i + 1] = _t2[_i01];                                          \
            pf[4 * _i + 2] = _t2[_i10];                                          \
            pf[4 * _i + 3] = _t2[_i11];                                          \
        }                                                                        \
    }

// Layer1 -> LDS -> layer2 -> LDS -> layer3 -> sigmoid -> out. Takes xb by
// value; no loop-carried state, safe as a function.
static __device__ __forceinline__ void mlp_tile(
    u16x8 xb, int pt, int quad, int lanelo,
    unsigned short* __restrict__ hp, const unsigned short* __restrict__ w2T,
    const u16x8* __restrict__ a1, const u16x8* __restrict__ a3,
    const float* __restrict__ b1s, const float* __restrict__ b2s,
    const float* __restrict__ b3v, float* __restrict__ out)
{
    f32x4 z = {0.f, 0.f, 0.f, 0.f};
    // ---- layer 1: 8 MFMAs, K=32 ----
    f32x4 d[8];
#pragma unroll
    for (int mt = 0; mt < 8; ++mt) d[mt] = mfma16(a1[mt], xb, z);
#pragma unroll
    for (int mt = 0; mt < 8; ++mt) {
        u16x4 pk;
#pragma unroll
        for (int r = 0; r < 4; ++r) {
            float hv = d[mt][r] + b1s[mt * 16 + quad * 4 + r];
            pk[r] = f2bf(fmaxf(hv, 0.f));
        }
        *(u16x4*)(hp + mt * 16 + quad * 4) = pk;
    }
    // ---- layer 2: K=128 in 4 steps x 8 m-tiles (wave-internal LDS, DS in-order) ----
    f32x4 e[8];
#pragma unroll
    for (int mt = 0; mt < 8; ++mt) e[mt] = z;
#pragma unroll
    for (int ks = 0; ks < 4; ++ks) {
        u16x8 bb = *(const u16x8*)(hp + ks * 32 + quad * 8);
#pragma unroll
        for (int mt = 0; mt < 8; ++mt) {
            u16x8 aa = *(const u16x8*)(w2T + (mt * 16 + lanelo) * 136 + ks * 32 + quad * 8);
            e[mt] = mfma16(aa, bb, e[mt]);
        }
    }
#pragma unroll
    for (int mt = 0; mt < 8; ++mt) {
        u16x4 pk;
#pragma unroll
        for (int r = 0; r < 4; ++r) {
            float hv = e[mt][r] + b2s[mt * 16 + quad * 4 + r];
            pk[r] = f2bf(fmaxf(hv, 0.f));
        }
        *(u16x4*)(hp + mt * 16 + quad * 4) = pk;
    }
    // ---- layer 3: 4 MFMAs, rows 0..2 = RGB logits ----
    f32x4 o3 = z;
#pragma unroll
    for (int ks = 0; ks < 4; ++ks) {
        u16x8 bb = *(const u16x8*)(hp + ks * 32 + quad * 8);
        o3 = mfma16(a3[ks], bb, o3);
    }
    if (quad == 0) {   // D rows 0..2 live in quad 0, r=0..2
        float* op = out + (size_t)pt * 3;
#pragma unroll
        for (int r = 0; r < 3; ++r) {
            float lv = o3[r] + b3v[r];
            op[r] = 1.f / (1.f + expf(-lv));
        }
    }
}

// LDS: w2T[out 128][in 136 pad] bf16 (34816 B) + h[4 waves][16 pts][136 pad]
// (17408 B) + biases (1024 B) = 53248 B -> 3 blocks/CU (LDS-bound).
// VGPR: (256,3) caps ~168; demand ~150 (a1 32 + a3 16 + pf 32 + acc 32 + misc).
__global__ __launch_bounds__(256, 3)
void fused_ngp_mlp(const float* __restrict__ uv, const float* __restrict__ tables,
                   const float* __restrict__ w1, const float* __restrict__ b1,
                   const float* __restrict__ w2, const float* __restrict__ b2,
                   const float* __restrict__ w3, const float* __restrict__ b3,
                   float* __restrict__ out, int npts)
{
    __shared__ __align__(16) unsigned short w2T[128 * 136];
    __shared__ __align__(16) unsigned short hbuf[4 * 16 * 136];
    __shared__ float b1s[128], b2s[128];

    const int tid = threadIdx.x;
    for (int e2 = tid; e2 < 128 * 128; e2 += 256) {     // w2 is [in][out]; store w2T[out][in]
        int i = e2 >> 7, o = e2 & 127;
        w2T[o * 136 + i] = f2bf(w2[e2]);
    }
    if (tid < 128) { b1s[tid] = b1[tid]; b2s[tid] = b2[tid]; }
    __syncthreads();   // only barrier: w2T/bias init. hbuf is per-wave after this.

    const int lane = tid & 63;
    const int wv = tid >> 6;
    const int lanelo = lane & 15;
    const int quad = lane >> 4;

    // Register-resident A-fragments: layer 1 (w1^T [128x32]) and layer 3 (w3^T [3x128]).
    u16x8 a1[8];
#pragma unroll
    for (int mt = 0; mt < 8; ++mt)
#pragma unroll
        for (int j = 0; j < 8; ++j)
            a1[mt][j] = f2bf(w1[(quad * 8 + j) * 128 + mt * 16 + lanelo]);  // w1[k][m]

    u16x8 a3[4];
#pragma unroll
    for (int ks = 0; ks < 4; ++ks)
#pragma unroll
        for (int j = 0; j < 8; ++j) {
            int k = ks * 32 + quad * 8 + j;
            a3[ks][j] = (lanelo < 3) ? f2bf(w3[k * 3 + lanelo]) : (unsigned short)0;  // w3[k][m]
        }

    float b3v[3] = {b3[0], b3[1], b3[2]};

    const int NT = npts >> 4;                 // 16-point tiles
    const int nwaves = gridDim.x * 4;
    const int gwave = blockIdx.x * 4 + wv;

    unsigned short* hp = hbuf + (wv * 16 + lanelo) * 136;   // this lane's point-row
    const float2* t2base = (const float2*)tables;
    const float2* uv2 = (const float2*)uv;

    // ---- depth-1/2 pipelined persistent loop; state in plain locals ----
    int tile = gwave;
    if (tile >= NT) return;
    float2 pf[16];
    float pwx[4], pwy[4];
    ISSUE_GATHERS((tile << 4) + lanelo)
    for (;;) {
        int pt = (tile << 4) + lanelo;
        // interp consumes pf (vmcnt wait lands here), freeing it for reissue
        u16x8 xb;
#pragma unroll
        for (int i = 0; i < 4; ++i) {
            float wx = pwx[i], wy = pwy[i];
            float w00 = (1.f - wx) * (1.f - wy);
            float w01 = (1.f - wx) * wy;
            float w10 = wx * (1.f - wy);
            float w11 = wx * wy;
            float2 f00 = pf[4 * i + 0], f01 = pf[4 * i + 1];
            float2 f10 = pf[4 * i + 2], f11 = pf[4 * i + 3];
            float g0 = w00 * f00.x + w01 * f01.x + w10 * f10.x + w11 * f11.x;
            float g1 = w00 * f00.y + w01 * f01.y + w10 * f10.y + w11 * f11.y;
            xb[2 * i]     = f2bf(g0);
            xb[2 * i + 1] = f2bf(g1);
        }
        int nxt = tile + nwaves;
        bool more = nxt < NT;
        if (more)
            ISSUE_GATHERS((nxt << 4) + lanelo)   // in flight across the MLP below
        mlp_tile(xb, pt, quad, lanelo, hp, w2T, a1, a3, b1s, b2s, b3v, out);
        if (!more) return;
        tile = nxt;
    }
}

extern "C" void kernel_launch(void* const* d_in, const int* in_sizes, int n_in,
                              void* d_out, int out_size, void* d_ws, size_t ws_size,
                              hipStream_t stream) {
    const float* uv     = (const float*)d_in[0];
    const float* tables = (const float*)d_in[1];
    const float* w1     = (const float*)d_in[2];
    const float* b1     = (const float*)d_in[3];
    const float* w2     = (const float*)d_in[4];
    const float* b2     = (const float*)d_in[5];
    const float* w3     = (const float*)d_in[6];
    const float* b3     = (const float*)d_in[7];
    float* out = (float*)d_out;
    int npts = in_sizes[0] / 2;          // uv is [N,2]
    // Persistent: 768 blocks = 3/CU exactly (LDS-bound residency); 3072 waves,
    // 65536 tiles -> ~21.3 tiles/wave, pipeline warms once per wave.
    hipLaunchKernelGGL(fused_ngp_mlp, dim3(768), dim3(256), 0, stream,
                       uv, tables, w1, b1, w2, b2, w3, b3, out, npts);
}

// Round 5
// 984.425 us; speedup vs baseline: 1.2531x; 1.2531x over previous
//
#include <hip/hip_runtime.h>

// Instant-NGP 2D hashgrid (L=16, T=2^20, F=2, N_MIN=16, b=2) + MLP 32->128->128->3.
// R5: FETCH-bound discovery — all prior rounds ran at exactly ~3.47 TB/s of
// L2-miss bandwidth (dur = FETCH/3.47TB/s within 3% on R1-R4). The lever is
// reducing L2-miss bytes, not latency hiding. Plan:
//   K1: tables f32 -> bf16 in d_ws (a bf16 level table = 4MB = one XCD L2).
//   K2: level-partitioned encode: block b handles levels {2*(b&7), +1}
//       (blockIdx%8 ~ XCD round-robin heuristic), level-major so each XCD's
//       active table stays L2-resident -> gathers hit L2, compulsory fetch
//       drops from ~1.5GB to ~100MB. Writes feats[16][N] u32 planes (2xbf16).
//   K3: R1's proven MFMA MLP, feats plane loads instead of gathers.
// Fallback: fused single kernel (R1 structure) if ws_size < 128MiB.
//
// mfma_f32_16x16x32_bf16 layouts (HW-verified per guide):
//   A[m][k]: m=lane&15, k=(lane>>4)*8+j   B[k][n]: n=lane&15, k=(lane>>4)*8+j
//   D[m][n]: n=lane&15, m=(lane>>4)*4+r
// Lane (quad,lo) consumes levels 4q..4q+3 of point lo == its B-fragment.

#define T_SIZE  (1u << 20)
#define HASH_Y  2654435761u
#define NLVL    16

typedef __bf16 bf16x8 __attribute__((ext_vector_type(8)));
typedef float f32x4 __attribute__((ext_vector_type(4)));
typedef unsigned short u16x8 __attribute__((ext_vector_type(8)));
typedef unsigned short u16x4 __attribute__((ext_vector_type(4)));
typedef unsigned int uint32;

static __device__ __forceinline__ unsigned short f2bf(float f) {
    union { float f; unsigned u; } v; v.f = f;
    unsigned u = v.u;
    u += 0x7fffu + ((u >> 16) & 1u);   // round-to-nearest-even
    return (unsigned short)(u >> 16);
}
static __device__ __forceinline__ uint32 pack2(float a, float b) {
    return (uint32)f2bf(a) | ((uint32)f2bf(b) << 16);
}
static __device__ __forceinline__ float bflo(uint32 u) {
    union { unsigned u; float f; } v; v.u = u << 16; return v.f;
}
static __device__ __forceinline__ float bfhi(uint32 u) {
    union { unsigned u; float f; } v; v.u = u & 0xffff0000u; return v.f;
}
static __device__ __forceinline__ f32x4 mfma16(u16x8 a, u16x8 b, f32x4 c) {
    return __builtin_amdgcn_mfma_f32_16x16x32_bf16(
        __builtin_bit_cast(bf16x8, a), __builtin_bit_cast(bf16x8, b), c, 0, 0, 0);
}

// ---------------- K1: convert tables f32 -> packed bf16 pairs ----------------
__global__ __launch_bounds__(256, 8)
void cvt_tables(const float4* __restrict__ in, uint2* __restrict__ out, int n4) {
    int stride = gridDim.x * blockDim.x;
    for (int i = blockIdx.x * blockDim.x + threadIdx.x; i < n4; i += stride) {
        float4 f = in[i];
        uint2 o;
        o.x = pack2(f.x, f.y);
        o.y = pack2(f.z, f.w);
        out[i] = o;
    }
}

// ---------------- K2: level-partitioned encode ----------------
// grid = 2048 blocks (all co-resident: tiny VGPR/LDS). Block b: levels
// 2*(b&7), 2*(b&7)+1 processed sequentially (one 4MB table hot at a time).
__global__ __launch_bounds__(256, 8)
void encode_lvl(const float2* __restrict__ uv2, const uint32* __restrict__ tbf,
                uint32* __restrict__ feats, int npts) {
    const int xcd = blockIdx.x & 7;
    const int widx = blockIdx.x >> 3;
    const int base = widx * 256 + threadIdx.x;
    const int stride = (gridDim.x >> 3) * 256;
#pragma unroll
    for (int li = 0; li < 2; ++li) {
        const int lvl = 2 * xcd + li;
        const unsigned res = 16u << lvl;
        const unsigned rp1 = res + 1u;
        const bool dense = lvl < 6;            // (res+1)^2 <= T
        const unsigned mask = T_SIZE - 1u;
        const uint32* tb = tbf + (size_t)lvl * T_SIZE;
        uint32* fp = feats + (size_t)lvl * npts;
        const float fres = (float)res;
        for (int pt = base; pt < npts; pt += stride) {
            float2 p = uv2[pt];
            float px = p.x * fres, py = p.y * fres;
            float fx = floorf(px), fy = floorf(py);
            float wx = px - fx, wy = py - fy;
            unsigned cx = (unsigned)fx, cy = (unsigned)fy;
            unsigned hy0 = cy * HASH_Y, hy1 = (cy + 1u) * HASH_Y;
            unsigned i00 = dense ? (cx + cy * rp1)             : ((cx ^ hy0) & mask);
            unsigned i01 = dense ? (cx + (cy + 1u) * rp1)      : ((cx ^ hy1) & mask);
            unsigned i10 = dense ? (cx + 1u + cy * rp1)        : (((cx + 1u) ^ hy0) & mask);
            unsigned i11 = dense ? (cx + 1u + (cy + 1u) * rp1) : (((cx + 1u) ^ hy1) & mask);
            uint32 e00 = tb[i00], e01 = tb[i01], e10 = tb[i10], e11 = tb[i11];
            float w00 = (1.f - wx) * (1.f - wy);
            float w01 = (1.f - wx) * wy;
            float w10 = wx * (1.f - wy);
            float w11 = wx * wy;
            float g0 = w00 * bflo(e00) + w01 * bflo(e01) + w10 * bflo(e10) + w11 * bflo(e11);
            float g1 = w00 * bfhi(e00) + w01 * bfhi(e01) + w10 * bfhi(e10) + w11 * bfhi(e11);
            fp[pt] = pack2(g0, g1);
        }
    }
}

// ---------------- shared MLP tile body (proven in R1/R4) ----------------
static __device__ __forceinline__ void mlp_tile(
    u16x8 xb, int pt, int quad, int lanelo,
    unsigned short* __restrict__ hp, const unsigned short* __restrict__ w2T,
    const u16x8* __restrict__ a1, const u16x8* __restrict__ a3,
    const float* __restrict__ b1s, const float* __restrict__ b2s,
    const float* __restrict__ b3v, float* __restrict__ out)
{
    f32x4 z = {0.f, 0.f, 0.f, 0.f};
    f32x4 d[8];
#pragma unroll
    for (int mt = 0; mt < 8; ++mt) d[mt] = mfma16(a1[mt], xb, z);
#pragma unroll
    for (int mt = 0; mt < 8; ++mt) {
        u16x4 pk;
#pragma unroll
        for (int r = 0; r < 4; ++r) {
            float hv = d[mt][r] + b1s[mt * 16 + quad * 4 + r];
            pk[r] = f2bf(fmaxf(hv, 0.f));
        }
        *(u16x4*)(hp + mt * 16 + quad * 4) = pk;
    }
    f32x4 e[8];
#pragma unroll
    for (int mt = 0; mt < 8; ++mt) e[mt] = z;
#pragma unroll
    for (int ks = 0; ks < 4; ++ks) {
        u16x8 bb = *(const u16x8*)(hp + ks * 32 + quad * 8);
#pragma unroll
        for (int mt = 0; mt < 8; ++mt) {
            u16x8 aa = *(const u16x8*)(w2T + (mt * 16 + lanelo) * 136 + ks * 32 + quad * 8);
            e[mt] = mfma16(aa, bb, e[mt]);
        }
    }
#pragma unroll
    for (int mt = 0; mt < 8; ++mt) {
        u16x4 pk;
#pragma unroll
        for (int r = 0; r < 4; ++r) {
            float hv = e[mt][r] + b2s[mt * 16 + quad * 4 + r];
            pk[r] = f2bf(fmaxf(hv, 0.f));
        }
        *(u16x4*)(hp + mt * 16 + quad * 4) = pk;
    }
    f32x4 o3 = z;
#pragma unroll
    for (int ks = 0; ks < 4; ++ks) {
        u16x8 bb = *(const u16x8*)(hp + ks * 32 + quad * 8);
        o3 = mfma16(a3[ks], bb, o3);
    }
    if (quad == 0) {
        float* op = out + (size_t)pt * 3;
#pragma unroll
        for (int r = 0; r < 3; ++r) {
            float lv = o3[r] + b3v[r];
            op[r] = 1.f / (1.f + expf(-lv));
        }
    }
}

// Common per-wave init: w2T/bias staging + a1/a3 fragments. Returns via refs.
#define MLP_INIT()                                                               \
    __shared__ __align__(16) unsigned short w2T[128 * 136];                      \
    __shared__ __align__(16) unsigned short hbuf[4 * 16 * 136];                  \
    __shared__ float b1s[128], b2s[128];                                         \
    const int tid = threadIdx.x;                                                 \
    for (int e2 = tid; e2 < 128 * 128; e2 += 256) {                              \
        int i_ = e2 >> 7, o_ = e2 & 127;                                         \
        w2T[o_ * 136 + i_] = f2bf(w2[e2]);                                       \
    }                                                                            \
    if (tid < 128) { b1s[tid] = b1[tid]; b2s[tid] = b2[tid]; }                   \
    __syncthreads();                                                             \
    const int lane = tid & 63;                                                   \
    const int wv = tid >> 6;                                                     \
    const int lanelo = lane & 15;                                                \
    const int quad = lane >> 4;                                                  \
    u16x8 a1[8];                                                                 \
    _Pragma("unroll")                                                            \
    for (int mt = 0; mt < 8; ++mt)                                               \
        _Pragma("unroll")                                                        \
        for (int j = 0; j < 8; ++j)                                              \
            a1[mt][j] = f2bf(w1[(quad * 8 + j) * 128 + mt * 16 + lanelo]);       \
    u16x8 a3[4];                                                                 \
    _Pragma("unroll")                                                            \
    for (int ks = 0; ks < 4; ++ks)                                               \
        _Pragma("unroll")                                                        \
        for (int j = 0; j < 8; ++j) {                                            \
            int k_ = ks * 32 + quad * 8 + j;                                     \
            a3[ks][j] = (lanelo < 3) ? f2bf(w3[k_ * 3 + lanelo]) : (unsigned short)0; \
        }                                                                        \
    float b3v[3] = {b3[0], b3[1], b3[2]};                                        \
    unsigned short* hp = hbuf + (wv * 16 + lanelo) * 136;

// ---------------- K3: MLP over precomputed features ----------------
__global__ __launch_bounds__(256, 3)
void mlp_feats(const uint32* __restrict__ feats,
               const float* __restrict__ w1, const float* __restrict__ b1,
               const float* __restrict__ w2, const float* __restrict__ b2,
               const float* __restrict__ w3, const float* __restrict__ b3,
               float* __restrict__ out, int npts)
{
    MLP_INIT();
    const int NT = npts >> 4;
    const int nwaves = gridDim.x * 4;
    for (int tile = blockIdx.x * 4 + wv; tile < NT; tile += nwaves) {
        int pt = (tile << 4) + lanelo;
        u16x8 xb;
#pragma unroll
        for (int i = 0; i < 4; ++i) {
            uint32 u = feats[(size_t)(quad * 4 + i) * npts + pt];
            xb[2 * i]     = (unsigned short)(u & 0xffffu);
            xb[2 * i + 1] = (unsigned short)(u >> 16);
        }
        mlp_tile(xb, pt, quad, lanelo, hp, w2T, a1, a3, b1s, b2s, b3v, out);
    }
}

// ---------------- fallback: fused gather+MLP (R1 structure) ----------------
__global__ __launch_bounds__(256, 3)
void fused_fallback(const float* __restrict__ uv, const float* __restrict__ tables,
                    const float* __restrict__ w1, const float* __restrict__ b1,
                    const float* __restrict__ w2, const float* __restrict__ b2,
                    const float* __restrict__ w3, const float* __restrict__ b3,
                    float* __restrict__ out, int npts)
{
    MLP_INIT();
    const int NT = npts >> 4;
    const int nwaves = gridDim.x * 4;
    const float2* t2base = (const float2*)tables;
    const float2* uv2 = (const float2*)uv;
    for (int tile = blockIdx.x * 4 + wv; tile < NT; tile += nwaves) {
        int pt = (tile << 4) + lanelo;
        float2 p = uv2[pt];
        u16x8 xb;
#pragma unroll
        for (int i = 0; i < 4; ++i) {
            int lvl = (quad << 2) + i;
            unsigned res = 16u << lvl;
            float px = p.x * (float)res, py = p.y * (float)res;
            float fx = floorf(px), fy = floorf(py);
            float wx = px - fx, wy = py - fy;
            unsigned cx = (unsigned)fx, cy = (unsigned)fy;
            unsigned rp1 = res + 1u;
            unsigned hy0 = cy * HASH_Y, hy1 = (cy + 1u) * HASH_Y;
            const unsigned mask = T_SIZE - 1u;
            bool dense = lvl < 6;
            unsigned i00 = dense ? (cx + cy * rp1)             : ((cx ^ hy0) & mask);
            unsigned i01 = dense ? (cx + (cy + 1u) * rp1)      : ((cx ^ hy1) & mask);
            unsigned i10 = dense ? (cx + 1u + cy * rp1)        : (((cx + 1u) ^ hy0) & mask);
            unsigned i11 = dense ? (cx + 1u + (cy + 1u) * rp1) : (((cx + 1u) ^ hy1) & mask);
            const float2* t2 = t2base + (size_t)lvl * T_SIZE;
            float2 f00 = t2[i00], f01 = t2[i01], f10 = t2[i10], f11 = t2[i11];
            float w00 = (1.f - wx) * (1.f - wy);
            float w01 = (1.f - wx) * wy;
            float w10 = wx * (1.f - wy);
            float w11 = wx * wy;
            float g0 = w00 * f00.x + w01 * f01.x + w10 * f10.x + w11 * f11.x;
            float g1 = w00 * f00.y + w01 * f01.y + w10 * f10.y + w11 * f11.y;
            xb[2 * i]     = f2bf(g0);
            xb[2 * i + 1] = f2bf(g1);
        }
        mlp_tile(xb, pt, quad, lanelo, hp, w2T, a1, a3, b1s, b2s, b3v, out);
    }
}

extern "C" void kernel_launch(void* const* d_in, const int* in_sizes, int n_in,
                              void* d_out, int out_size, void* d_ws, size_t ws_size,
                              hipStream_t stream) {
    const float* uv     = (const float*)d_in[0];
    const float* tables = (const float*)d_in[1];
    const float* w1     = (const float*)d_in[2];
    const float* b1     = (const float*)d_in[3];
    const float* w2     = (const float*)d_in[4];
    const float* b2     = (const float*)d_in[5];
    const float* w3     = (const float*)d_in[6];
    const float* b3     = (const float*)d_in[7];
    float* out = (float*)d_out;
    int npts = in_sizes[0] / 2;

    const size_t TB_BYTES = (size_t)NLVL * T_SIZE * 4;          // 64 MiB bf16 tables
    const size_t FT_BYTES = (size_t)NLVL * (size_t)npts * 4;    // 64 MiB features
    if (ws_size < TB_BYTES + FT_BYTES) {
        hipLaunchKernelGGL(fused_fallback, dim3(2048), dim3(256), 0, stream,
                           uv, tables, w1, b1, w2, b2, w3, b3, out, npts);
        return;
    }
    uint32* tbf   = (uint32*)d_ws;
    uint32* feats = (uint32*)((char*)d_ws + TB_BYTES);

    int n4 = in_sizes[1] / 4;                                   // float4 groups
    hipLaunchKernelGGL(cvt_tables, dim3(4096), dim3(256), 0, stream,
                       (const float4*)tables, (uint2*)tbf, n4);
    hipLaunchKernelGGL(encode_lvl, dim3(2048), dim3(256), 0, stream,
                       (const float2*)uv, tbf, feats, npts);
    hipLaunchKernelGGL(mlp_feats, dim3(2048), dim3(256), 0, stream,
                       feats, w1, b1, w2, b2, w3, b3, out, npts);
}